// Round 1
// baseline (17.355 us; speedup 1.0000x reference)
//
#include <hip/hip_runtime.h>

// The entire reference computation collapses: exp(y - y) == 1 for all finite y,
// so output == sigmoid(SCALE * 1) == sigmoid(2.0) everywhere. The conv is dead.
// This is a pure constant-fill: 16*64*128*128 floats = 64 MiB of writes.

__global__ void fill_const_vec4(float4* __restrict__ out, int n4, float val) {
    const float4 v = make_float4(val, val, val, val);
    int stride = gridDim.x * blockDim.x;
    for (int i = blockIdx.x * blockDim.x + threadIdx.x; i < n4; i += stride) {
        out[i] = v;
    }
}

__global__ void fill_const_tail(float* __restrict__ out, int start, int n, float val) {
    int i = start + blockIdx.x * blockDim.x + threadIdx.x;
    if (i < n) out[i] = val;
}

extern "C" void kernel_launch(void* const* d_in, const int* in_sizes, int n_in,
                              void* d_out, int out_size, void* d_ws, size_t ws_size,
                              hipStream_t stream) {
    float* out = (float*)d_out;

    // sigmoid(2.0) computed in double, rounded to float
    const float val = (float)(1.0 / (1.0 + exp(-2.0)));  // 0.8807970779778823

    int n4 = out_size / 4;          // 4,194,304 float4 for this problem
    int tail_start = n4 * 4;

    if (n4 > 0) {
        int threads = 256;
        int max_blocks = 2048;       // 256 CUs * 8 blocks; grid-stride the rest
        int blocks = (n4 + threads - 1) / threads;
        if (blocks > max_blocks) blocks = max_blocks;
        fill_const_vec4<<<blocks, threads, 0, stream>>>((float4*)out, n4, val);
    }
    if (tail_start < out_size) {
        int rem = out_size - tail_start;
        int threads = 256;
        int blocks = (rem + threads - 1) / threads;
        fill_const_tail<<<blocks, threads, 0, stream>>>(out, tail_start, out_size, val);
    }
}

// Round 3
// 16.217 us; speedup vs baseline: 1.0701x; 1.0701x over previous
//
#include <hip/hip_runtime.h>

// The entire reference computation collapses: exp(y - y) == 1 for all finite y,
// so output == sigmoid(SCALE * 1) == sigmoid(2.0) everywhere. The conv is dead.
// Pure constant-fill of 16*64*128*128 floats = 64 MiB of writes.
//
// Round 2 -> 3: __builtin_nontemporal_store needs a native clang vector type,
// not HIP's float4 struct. Use ext_vector_type(4).

typedef float fvec4 __attribute__((ext_vector_type(4)));

__global__ void fill_const_1x4(fvec4* __restrict__ out, int n4, float val) {
    int i = blockIdx.x * blockDim.x + threadIdx.x;
    if (i < n4) {
        fvec4 v = {val, val, val, val};
        __builtin_nontemporal_store(v, &out[i]);
    }
}

__global__ void fill_const_tail(float* __restrict__ out, int start, int n, float val) {
    int i = start + blockIdx.x * blockDim.x + threadIdx.x;
    if (i < n) out[i] = val;
}

extern "C" void kernel_launch(void* const* d_in, const int* in_sizes, int n_in,
                              void* d_out, int out_size, void* d_ws, size_t ws_size,
                              hipStream_t stream) {
    float* out = (float*)d_out;

    // sigmoid(2.0) computed in double, rounded to float
    const float val = (float)(1.0 / (1.0 + exp(-2.0)));  // 0.8807970779778823

    int n4 = out_size / 4;          // 4,194,304 fvec4 for this problem
    int tail_start = n4 * 4;

    if (n4 > 0) {
        const int threads = 256;
        int blocks = (n4 + threads - 1) / threads;   // 16384 for this problem
        fill_const_1x4<<<blocks, threads, 0, stream>>>((fvec4*)out, n4, val);
    }
    if (tail_start < out_size) {
        int rem = out_size - tail_start;
        const int threads = 256;
        int blocks = (rem + threads - 1) / threads;
        fill_const_tail<<<blocks, threads, 0, stream>>>(out, tail_start, out_size, val);
    }
}